// Round 7
// baseline (215.417 us; speedup 1.0000x reference)
//
#include <hip/hip_runtime.h>

// x(8,64,8,64,64) fp32, w_q(32,64), w_kv(64,64)
// f = d*8+n (256), p = y*64+xi (4096), p2 = y2*32+x2 (1024)

typedef __attribute__((ext_vector_type(8))) short short8;
typedef __attribute__((ext_vector_type(4))) float floatx4;
typedef __attribute__((ext_vector_type(2))) unsigned uintx2;

__device__ __forceinline__ short f2bf(float f) {  // RNE, finite only
    unsigned u = __builtin_bit_cast(unsigned, f);
    u += 0x7fffu + ((u >> 16) & 1u);
    return (short)(u >> 16);
}
__device__ __forceinline__ unsigned pack2bf(float a, float b) {
    return (unsigned)(unsigned short)f2bf(a) | ((unsigned)(unsigned short)f2bf(b) << 16);
}

// ---------------- proj v3: zero-LDS, zero-barrier, thread-per-position ----------------
// grid 640 x 256. Blocks 0..127: k+v for the 8192 strided positions. Blocks 128..639: q
// for all 32768 positions. Lane = nq*16 + x4: thread owns position, n in {2nq, 2nq+1}.
// Weights via uniform s_load (K$); x loads coalesced global (vmcnt only); norm over
// (d,n) = 64 local values + shfl_xor(16,32) across the 4 nq lanes. No LDS at all.
__global__ __launch_bounds__(256) void proj(const float* __restrict__ x,
                                            const float* __restrict__ wq,
                                            const float* __restrict__ wkv,
                                            short* __restrict__ qraw,
                                            short* __restrict__ kraw,
                                            short* __restrict__ vraw) {
    int t = threadIdx.x;
    int lane = t & 63, w = t >> 6;
    int x4 = lane & 15, nq = (lane >> 4) & 3;   // n = 2*nq + h

    if (blockIdx.x >= 128) {
        // ---- q role: 512 blocks x 64 positions ----
        int p_lin = (blockIdx.x - 128) * 64 + w * 16 + x4;
        int b = p_lin >> 12, p = p_lin & 4095;
        const float* xb = x + (size_t)b * 2097152 + (2 * nq) * 4096 + p;
        float o[64];                             // [h][d]
#pragma unroll
        for (int i = 0; i < 64; ++i) o[i] = 0.f;
        float nx0 = xb[0], nx1 = xb[4096];
#pragma unroll 1
        for (int c2 = 0; c2 < 32; ++c2) {
            int cu = __builtin_amdgcn_readfirstlane(c2);
            float a0 = nx0, a1 = nx1;
            float b0 = xb[(size_t)(2 * cu + 1) * 32768];
            float b1 = xb[(size_t)(2 * cu + 1) * 32768 + 4096];
            if (c2 < 31) {                       // prefetch next pair
                nx0 = xb[(size_t)(2 * cu + 2) * 32768];
                nx1 = xb[(size_t)(2 * cu + 2) * 32768 + 4096];
            }
#pragma unroll
            for (int d = 0; d < 32; ++d) {
                float2 wv = *(const float2*)(wq + d * 64 + 2 * cu);   // s_load_dwordx2
                o[d]      += wv.x * a0 + wv.y * b0;
                o[32 + d] += wv.x * a1 + wv.y * b1;
            }
        }
        float sq = 0.f;
#pragma unroll
        for (int i = 0; i < 64; ++i) sq += o[i] * o[i];
        sq += __shfl_xor(sq, 16);
        sq += __shfl_xor(sq, 32);
        float sc = 1.f / fmaxf(sqrtf(sq), 1e-12f);
        unsigned* qp = (unsigned*)(qraw + (size_t)(b * 4096 + p) * 256);
#pragma unroll
        for (int d = 0; d < 32; ++d)
            qp[d * 4 + nq] = pack2bf(o[d] * sc, o[32 + d] * sc);
    } else {
        // ---- kv role: 128 blocks x 64 strided positions ----
        int p2_lin = blockIdx.x * 64 + w * 16 + x4;
        int b = p2_lin >> 10, p2 = p2_lin & 1023;
        int y2 = p2 >> 5, x2 = p2 & 31;
        const float* xb = x + (size_t)b * 2097152 + (2 * nq) * 4096 + (2 * y2) * 64 + 2 * x2;
        float ko[64], vo[64];
#pragma unroll
        for (int i = 0; i < 64; ++i) { ko[i] = 0.f; vo[i] = 0.f; }
        float nx0 = xb[0], nx1 = xb[4096];
#pragma unroll 1
        for (int c = 0; c < 64; ++c) {
            int cu = __builtin_amdgcn_readfirstlane(c);
            float a0 = nx0, a1 = nx1;
            if (c < 63) {
                nx0 = xb[(size_t)(cu + 1) * 32768];
                nx1 = xb[(size_t)(cu + 1) * 32768 + 4096];
            }
#pragma unroll
            for (int d = 0; d < 32; ++d) {
                float wk = wkv[d * 64 + cu];              // s_load
                float wv2 = wkv[(32 + d) * 64 + cu];      // s_load
                ko[d]      += wk * a0;  ko[32 + d] += wk * a1;
                vo[d]      += wv2 * a0; vo[32 + d] += wv2 * a1;
            }
        }
        float sq = 0.f;
#pragma unroll
        for (int i = 0; i < 64; ++i) sq += ko[i] * ko[i];
        sq += __shfl_xor(sq, 16);
        sq += __shfl_xor(sq, 32);
        float sc = 1.f / fmaxf(sqrtf(sq), 1e-12f);
        unsigned* kp = (unsigned*)(kraw + (size_t)(b * 1024 + p2) * 256);
#pragma unroll
        for (int d = 0; d < 32; ++d)
            kp[d * 4 + nq] = pack2bf(ko[d] * sc, ko[32 + d] * sc);
        short* vp = vraw + (size_t)b * 262144 + p2;
#pragma unroll
        for (int d = 0; d < 32; ++d) {
            int f = d * 8 + 2 * nq;
            vp[(size_t)f * 1024]       = f2bf(vo[d]);
            vp[(size_t)(f + 1) * 1024] = f2bf(vo[32 + d]);
        }
    }
}

// ---------------- attn: R4 version (validated 65 us) — qtile=128, 4 waves, dbuf, 2 barriers/kc ----
// grid 256 = (b, qt of 128 rows), 256 threads
__global__ __launch_bounds__(256, 1) void attn(const short* __restrict__ qraw,
                                               const short* __restrict__ kraw,
                                               const short* __restrict__ vraw,
                                               float* __restrict__ out) {
    int b = blockIdx.x >> 5, qt = blockIdx.x & 31;
    int t = threadIdx.x, wv = t >> 6, lane = t & 63, l16 = lane & 15, quad = lane >> 4;

    __shared__ __align__(16) short k_s[2][32 * 264];  // [kp][f]+pad
    __shared__ __align__(16) short v_s[2][256 * 40];  // [f][kp]+pad
    __shared__ __align__(16) short p_s[2][128 * 40];  // [p][kp]+pad
    __shared__ float dsum[128];

    // Q fragments (prenormalized): wave owns p = qt*128 + wv*32 + pt*16 + l16
    short8 qf[2][8];
    const short* qb = qraw + ((size_t)b * 4096 + qt * 128 + wv * 32) * 256;
#pragma unroll
    for (int pt = 0; pt < 2; ++pt)
#pragma unroll
        for (int fs = 0; fs < 8; ++fs)
            qf[pt][fs] = *(const short8*)(qb + (pt * 16 + l16) * 256 + fs * 32 + quad * 8);

    floatx4 acc[8][4];  // [p-tile of 16][f-tile of 16 within wave's 64-f slice]
#pragma unroll
    for (int i = 0; i < 8; ++i)
#pragma unroll
        for (int j = 0; j < 4; ++j) acc[i][j] = (floatx4){0.f, 0.f, 0.f, 0.f};
    float dacc0 = 0.f, dacc1 = 0.f;

    int krow = t >> 3, kseg = t & 7;
    const short* kbase = kraw + ((size_t)b * 1024 + krow) * 256 + kseg * 32;
    const short* vbase = vraw + ((size_t)b * 256 + t) * 1024;

    short8 kst[4], vst[4];
#pragma unroll
    for (int j = 0; j < 4; ++j) {
        kst[j] = *(const short8*)(kbase + j * 8);
        vst[j] = *(const short8*)(vbase + j * 8);
    }
#pragma unroll
    for (int j = 0; j < 4; ++j) {
        *(short8*)(k_s[0] + krow * 264 + kseg * 32 + j * 8) = kst[j];
        *(short8*)(v_s[0] + t * 40 + j * 8) = vst[j];
    }
#pragma unroll
    for (int j = 0; j < 4; ++j) {
        kst[j] = *(const short8*)(kbase + (size_t)32 * 256 + j * 8);
        vst[j] = *(const short8*)(vbase + 32 + j * 8);
    }
    __syncthreads();

    for (int kc = 0; kc < 32; ++kc) {
        int cur = kc & 1, nxt = cur ^ 1;
        floatx4 cc0[2] = {(floatx4){0.f,0.f,0.f,0.f}, (floatx4){0.f,0.f,0.f,0.f}};
        floatx4 cc1[2] = {(floatx4){0.f,0.f,0.f,0.f}, (floatx4){0.f,0.f,0.f,0.f}};
#pragma unroll
        for (int kt = 0; kt < 2; ++kt) {
#pragma unroll
            for (int fs = 0; fs < 8; ++fs) {
                short8 a = *(const short8*)(k_s[cur] + (kt * 16 + l16) * 264 + fs * 32 + quad * 8);
                cc0[kt] = __builtin_amdgcn_mfma_f32_16x16x32_bf16(a, qf[0][fs], cc0[kt], 0, 0, 0);
                cc1[kt] = __builtin_amdgcn_mfma_f32_16x16x32_bf16(a, qf[1][fs], cc1[kt], 0, 0, 0);
            }
        }
#pragma unroll
        for (int kt = 0; kt < 2; ++kt) {
            float e0 = __expf(cc0[kt][0]), e1 = __expf(cc0[kt][1]);
            float e2 = __expf(cc0[kt][2]), e3 = __expf(cc0[kt][3]);
            dacc0 += (e0 + e1) + (e2 + e3);
            uintx2 w0; w0[0] = pack2bf(e0, e1); w0[1] = pack2bf(e2, e3);
            *(uintx2*)(p_s[cur] + (wv * 32 + l16) * 40 + kt * 16 + quad * 4) = w0;
            float f0 = __expf(cc1[kt][0]), f1 = __expf(cc1[kt][1]);
            float f2 = __expf(cc1[kt][2]), f3 = __expf(cc1[kt][3]);
            dacc1 += (f0 + f1) + (f2 + f3);
            uintx2 w1; w1[0] = pack2bf(f0, f1); w1[1] = pack2bf(f2, f3);
            *(uintx2*)(p_s[cur] + (wv * 32 + 16 + l16) * 40 + kt * 16 + quad * 4) = w1;
        }
        __syncthreads();   // B1: P[cur] ready

        if (kc < 31) {
#pragma unroll
            for (int j = 0; j < 4; ++j) {
                *(short8*)(k_s[nxt] + krow * 264 + kseg * 32 + j * 8) = kst[j];
                *(short8*)(v_s[nxt] + t * 40 + j * 8) = vst[j];
            }
        }
        short8 av[4];
#pragma unroll
        for (int fl = 0; fl < 4; ++fl)
            av[fl] = *(const short8*)(v_s[cur] + (wv * 64 + fl * 16 + l16) * 40 + quad * 8);
#pragma unroll
        for (int p2 = 0; p2 < 8; ++p2) {
            short8 bq = *(const short8*)(p_s[cur] + (p2 * 16 + l16) * 40 + quad * 8);
#pragma unroll
            for (int fl = 0; fl < 4; ++fl)
                acc[p2][fl] = __builtin_amdgcn_mfma_f32_16x16x32_bf16(av[fl], bq, acc[p2][fl], 0, 0, 0);
        }
        if (kc < 30) {
            int kp0n = (kc + 2) * 32;
#pragma unroll
            for (int j = 0; j < 4; ++j) {
                kst[j] = *(const short8*)(kbase + (size_t)kp0n * 256 + j * 8);
                vst[j] = *(const short8*)(vbase + kp0n + j * 8);
            }
        }
        __syncthreads();   // B2
    }
    dacc0 += __shfl_xor(dacc0, 16); dacc0 += __shfl_xor(dacc0, 32);
    dacc1 += __shfl_xor(dacc1, 16); dacc1 += __shfl_xor(dacc1, 32);
    if (quad == 0) {
        dsum[wv * 32 + l16] = dacc0;
        dsum[wv * 32 + 16 + l16] = dacc1;
    }
    __syncthreads();
    float* ob = out + (size_t)b * 1048576 + qt * 128;
#pragma unroll
    for (int p2 = 0; p2 < 8; ++p2) {
        float inv = 1.f / dsum[p2 * 16 + l16];
#pragma unroll
        for (int fl = 0; fl < 4; ++fl) {
            int f0 = wv * 64 + fl * 16 + quad * 4;
#pragma unroll
            for (int r = 0; r < 4; ++r)
                ob[(size_t)(f0 + r) * 4096 + p2 * 16 + l16] = acc[p2][fl][r] * inv;
        }
    }
}

extern "C" void kernel_launch(void* const* d_in, const int* in_sizes, int n_in,
                              void* d_out, int out_size, void* d_ws, size_t ws_size,
                              hipStream_t stream) {
    (void)in_sizes; (void)n_in; (void)out_size; (void)ws_size;
    const float* x   = (const float*)d_in[0];
    const float* wqp = (const float*)d_in[1];
    const float* wkv = (const float*)d_in[2];
    float* out = (float*)d_out;

    char* ws = (char*)d_ws;
    short* qraw = (short*)ws;                          // 16 MiB, [b][p][f] normalized bf16
    short* kraw = (short*)(ws + 16777216);             // 4 MiB,  [b][p2][f] normalized bf16
    short* vraw = (short*)(ws + 16777216 + 4194304);   // 4 MiB,  [b][f][p2] bf16

    proj<<<640, 256, 0, stream>>>(x, wqp, wkv, qraw, kraw, vraw);
    attn<<<256, 256, 0, stream>>>(qraw, kraw, vraw, out);
}